// Round 6
// baseline (358.113 us; speedup 1.0000x reference)
//
#include <hip/hip_runtime.h>

typedef _Float16 f16;
typedef __attribute__((ext_vector_type(8))) _Float16 f16x8;
typedef __attribute__((ext_vector_type(2))) __fp16 hf16x2;   // native type of cvt_pkrtz
typedef __attribute__((ext_vector_type(4))) float f32x4;

constexpr int C_ = 4, L_ = 1000, K_ = 64, NOUT = 986, NPOS = 16 * 986; // 15776
constexpr int TPB  = 256;                       // 4 waves
// R17: MTB 128->64 (wave owns 16 positions, nt dim gone). LDS/block 28.8K->15.5K ->
// 8 blocks/CU -> 8 waves/SIMD (2x TLP). R16 showed all pipes <25% per SIMD: latency-bound.
constexpr int MTB  = 64;                        // positions per block (16/wave)
constexpr int NBLK = (NPOS + MTB - 1) / MTB;    // 247
constexpr int AST  = 104;                       // row stride (f16): 208 B, 16B-aligned
constexpr int ACT_EL  = MTB * AST;              // 6656 f16
// LDS: act 13312 + bias(fp32) 1920 + head(fp32) 256 = 15488 B; 8 blocks/CU = 123904 <= 160K
constexpr size_t SMEM_BYTES = (size_t)ACT_EL * 2 + 480 * 4 + 64 * 4;

// ws: per layer l, per k: 96-row stride x AST cols fp16 W^T (row=out e, col=in d), zero-padded.
constexpr size_t WOFF[5]  = {0, 638976, 1277952, 1916928, 2555904};
constexpr int    WROWS[5] = {80, 96, 96, 80, 64};   // ceil16(DO)
constexpr int    DIv[5]   = {60, 72, 86, 86, 71};
constexpr int    DOv[5]   = {72, 86, 86, 71, 59};
// Precomputed L0 activation tiles appended after the weights (x-gather is 64x redundant
// across k). Stored in EXACT LDS layout (full 104-col rows incl. zero pads) so the main
// loop copies them with global_load_lds dwordx4.
constexpr size_t WTOT    = WOFF[4] + (size_t)K_ * 96 * AST;        // 3194880 f16
constexpr size_t ACT_WS  = WTOT;                                    // f16 index of tile region
constexpr size_t WS_NEED = (WTOT + (size_t)NBLK * ACT_EL) * 2;      // 9.68 MB

// prep decomposition (R16 structure): weight halves for 2x parallelism + act tile units.
constexpr int WUNITS = 5 * K_ * 2;   // 640
constexpr int AUNITS = NBLK;         // 247

__device__ __forceinline__ float gelu_f(float x) {
    // tanh-form gelu as x*sigmoid(2z); validated R4/R9/R10 (absmax 3.9e-3).
    // R12: -2*log2(e) folded into the polynomial constants -> direct v_exp_f32.
    float x2 = x * x;
    float ei = x * __builtin_fmaf(-0.1029433270f, x2, -2.3022082020f);
    float e  = __builtin_amdgcn_exp2f(ei);       // = exp(-2z)
    return x * __builtin_amdgcn_rcpf(e + 1.0f);
}

// A = W^T from global (L1/L2-resident: 4 waves of a block issue identical chunk addresses).
// B = this wave's 16 act rows from LDS. acc initialized with bias (e is lane-fixed in C).
// R17: no register prefetch (ap) — at 8 waves/SIMD, TLP hides the A-load latency, and the
// freed 24 VGPRs are what lets 8 waves fit the register file.
template<int KSTEPS, int MT>
__device__ __forceinline__ void layer_mm(const f16* __restrict__ actw,
                                         const f16* __restrict__ wsrc,
                                         f32x4 (&acc)[MT],
                                         const float* __restrict__ bl, int li, int q) {
#pragma unroll
    for (int mt = 0; mt < MT; mt++)
        acc[mt] = *(const f32x4*)(bl + mt * 16 + q * 4);    // broadcast across li
#pragma unroll
    for (int ks = 0; ks < KSTEPS; ks++) {
        const int koff = ks * 32 + q * 8;
        f16x8 a[MT];
#pragma unroll
        for (int mt = 0; mt < MT; mt++)
            a[mt] = *(const f16x8*)(wsrc + (mt * 16 + li) * AST + koff);
        f16x8 b = *(const f16x8*)(actw + li * AST + koff);  // ds_read_b128
#pragma unroll
        for (int mt = 0; mt < MT; mt++)
            acc[mt] = __builtin_amdgcn_mfma_f32_16x16x32_f16(a[mt], b, acc[mt], 0, 0, 0);
    }
}

// C/D: col(n=pos)=lane&15 -> row li of the wave's 16 act rows; row(m=e)=q*4+r.
// gelu (bias already in acc) + pkrtz + one ds_write_b64 per mt. Rows are wave-private:
// NO barrier between layers.
template<int MT>
__device__ __forceinline__ void epilogue(f32x4 (&acc)[MT], f16* __restrict__ actw,
                                         int li, int q) {
#pragma unroll
    for (int mt = 0; mt < MT; mt++) {
        const int eb = mt * 16 + q * 4;
        union { hf16x2 h[2]; unsigned long long u; } pk;
        pk.h[0] = __builtin_amdgcn_cvt_pkrtz(gelu_f(acc[mt][0]), gelu_f(acc[mt][1]));
        pk.h[1] = __builtin_amdgcn_cvt_pkrtz(gelu_f(acc[mt][2]), gelu_f(acc[mt][3]));
        *(unsigned long long*)(actw + li * AST + eb) = pk.u;   // 8B aligned
    }
}

// R13 weight prep: coalesced load -> padded LDS transpose -> vector store; e-half split (R16).
template<int L>
__device__ __forceinline__ void prep_one_half(const float* __restrict__ wsrc0,
                                              f16* __restrict__ ws, f16* __restrict__ wl,
                                              int k, int h, int tid) {
    constexpr int DI = DIv[L], DO = DOv[L], RW = WROWS[L];
    const float* wsrc = wsrc0 + (size_t)k * DI * DO;
    constexpr int TOT = DI * DO;
    constexpr int NIT = (TOT + 255) / 256;
    float v[NIT];
#pragma unroll
    for (int it = 0; it < NIT; it++) {
        int i = tid + it * 256;
        v[it] = (i < TOT) ? wsrc[i] : 0.f;
    }
#pragma unroll
    for (int it = 0; it < NIT; it++) {
        int i = tid + it * 256;
        if (i < TOT) {
            int d = i / DO, e = i - d * DO;
            wl[d * 87 + e] = (f16)v[it];
        }
    }
    __syncthreads();
    f16* dst = ws + WOFF[L] + (size_t)k * 96 * AST;
    constexpr int HCH = (RW / 2) * 13;           // 16B chunks in this half
    constexpr int NIT2 = (HCH + 255) / 256;
#pragma unroll
    for (int it = 0; it < NIT2; it++) {
        int c0 = tid + it * 256;
        if (c0 < HCH) {
            int c = h * HCH + c0;
            int e = c / 13, db = (c - e * 13) * 8;
            f16x8 vv;
#pragma unroll
            for (int j = 0; j < 8; j++) {
                int d = db + j;
                vv[j] = (e < DO && d < DI) ? wl[d * 87 + e] : (f16)0.f;
            }
            *(f16x8*)(dst + (size_t)c * 8) = vv;
        }
    }
}

// One mblk's L0 tile (64 rows), chunked per 16B output. Cols 0..59 = x-window, 60..103 = zero
// (covers the K=64 pad AND cols 80..95 that K=96 loops read but MT=5 epilogues never write).
__device__ __forceinline__ void prep_act(const float* __restrict__ x, f16* __restrict__ dst0,
                                         int m, int tid) {
    if (m >= NBLK) return;
    f16* dst = dst0 + (size_t)m * ACT_EL;
    const int base = m * MTB;
    constexpr int CHK = MTB * 13;                // 832 16B chunks per tile
    for (int i = tid; i < CHK; i += 256) {
        int r = i / 13, cc = (i - r * 13) * 8;
        int p = base + r; if (p > NPOS - 1) p = NPOS - 1;   // tail: duplicate last pos
        int b = p / NOUT, pos = p - b * NOUT;
        f16x8 vv;
#pragma unroll
        for (int j = 0; j < 8; j++) {
            int c = cc + j;
            float v = 0.f;
            if (c < 60) { int ch = c / 15, jj = c - ch * 15; v = x[(size_t)(b * C_ + ch) * L_ + pos + jj]; }
            vv[j] = (f16)v;
        }
        *(f16x8*)(dst + (size_t)r * AST + cc) = vv;
    }
}

// Flat prep grid: u < WUNITS -> weight half-panels; else act tiles.
__global__ __launch_bounds__(256) void prep_all(
    const float* __restrict__ w0, const float* __restrict__ w1, const float* __restrict__ w2,
    const float* __restrict__ w3, const float* __restrict__ w4,
    const float* __restrict__ x, f16* __restrict__ ws) {
    __shared__ f16 wl[86 * 87];
    const int tid = threadIdx.x, u = blockIdx.x;
    if (u < WUNITS) {
        const int k = (u >> 1) & 63, h = u & 1;
        switch (u >> 7) {
            case 0: prep_one_half<0>(w0, ws, wl, k, h, tid); break;
            case 1: prep_one_half<1>(w1, ws, wl, k, h, tid); break;
            case 2: prep_one_half<2>(w2, ws, wl, k, h, tid); break;
            case 3: prep_one_half<3>(w3, ws, wl, k, h, tid); break;
            default: prep_one_half<4>(w4, ws, wl, k, h, tid); break;
        }
    } else {
        prep_act(x, ws + ACT_WS, u - WUNITS, tid);
    }
}

// R17: __launch_bounds__(TPB,8) — 8 waves/SIMD. The whole round's thesis: R16 measured all
// per-SIMD pipes <25% (VALU 19, trans 22, MFMA 5) with waves stalled ~85% of residency ->
// latency-bound -> double TLP. Pipeline math unchanged; nt dimension removed.
template<bool PRE>
__global__ __launch_bounds__(TPB, 8) void mlp_main(
    const float* __restrict__ x,
    const float* __restrict__ b0, const float* __restrict__ b1, const float* __restrict__ b2,
    const float* __restrict__ b3, const float* __restrict__ b4,
    const float* __restrict__ hw, const float* __restrict__ hb,
    const f16* __restrict__ ws, float* __restrict__ out) {
    extern __shared__ char smemraw[];
    f16*   act   = (f16*)smemraw;                 // [64 pos][AST]
    float* biasl = (float*)(act + ACT_EL);        // 5 layers x 96 padded biases, fp32
    float* headl = biasl + 480;                   // 64 padded head weights, fp32

    const int tid = threadIdx.x, k = blockIdx.x, mblk = blockIdx.y;
    const int wv = tid >> 6, lane = tid & 63, li = lane & 15, q = lane >> 4;
    const int base = mblk * MTB;
    f16* actw = act + (wv * 16) * AST;            // this wave's 16 position rows
    const f16* wk = ws + (size_t)k * 96 * AST;    // k's weight panel base (per-layer via WOFF)

    // biases (padded to 96, fp32) + head weights into LDS
    for (int i = tid; i < 480; i += TPB) {
        int l = i / 96, e = i - l * 96;
        const float* bg = (l == 0) ? b0 : (l == 1) ? b1 : (l == 2) ? b2 : (l == 3) ? b3 : b4;
        int DO = (l == 0) ? 72 : (l == 1) ? 86 : (l == 2) ? 86 : (l == 3) ? 71 : 59;
        biasl[i] = (e < DO) ? bg[k * DO + e] : 0.f;
    }
    if (tid < 64) headl[tid] = (tid < 59) ? hw[tid] : 0.f;

    if constexpr (PRE) {
        // direct global->LDS copy of the precomputed tile: 13312 B = 13 x (64 lanes x 16 B).
        const f16* src = ws + ACT_WS + (size_t)mblk * ACT_EL;
        for (int c = wv; c < 13; c += 4) {
            __builtin_amdgcn_global_load_lds(
                (const __attribute__((address_space(1))) void*)(src + c * 512 + lane * 8),
                (__attribute__((address_space(3))) void*)(act + c * 512), 16, 0, 0);
        }
    } else {
        // fallback (ws too small): in-kernel gather.
        const int b0i = base / NOUT;
        const int thr = (b0i + 1) * NOUT;
        for (int i = tid; i < 64 * MTB; i += TPB) {
            int d = i >> 6, r = i & (MTB - 1);
            int p = base + r; if (p > NPOS - 1) p = NPOS - 1;
            int b = (p >= thr) ? b0i + 1 : b0i;
            int pos = p - b * NOUT;
            float v = 0.f;
            if (d < 60) { int c = d / 15, j = d - c * 15; v = x[(size_t)(b * C_ + c) * L_ + pos + j]; }
            act[r * AST + d] = (f16)v;
        }
        for (int i = tid; i < MTB * 2; i += TPB) {
            int r = i >> 1, cc = (i & 1) << 3;
            *(f16x8*)(act + r * AST + 80 + cc) = f16x8{0,0,0,0,0,0,0,0};
        }
    }
    const float hb0 = hb[0];
    __syncthreads();     // the ONLY barrier (also drains vmcnt for the global_load_lds copy)

    f32x4 acc[6];
    f32x4 (&acc5)[5] = reinterpret_cast<f32x4 (&)[5]>(acc);

    layer_mm<2, 5>(actw, wk + WOFF[0], acc5, biasl + 0 * 96, li, q);   // L0: K=64, DO=72
    epilogue<5>(acc5, actw, li, q);
    layer_mm<3, 6>(actw, wk + WOFF[1], acc,  biasl + 1 * 96, li, q);   // L1: K=96(72), DO=86
    epilogue<6>(acc, actw, li, q);
    layer_mm<3, 6>(actw, wk + WOFF[2], acc,  biasl + 2 * 96, li, q);   // L2: K=96(86), DO=86
    epilogue<6>(acc, actw, li, q);
    layer_mm<3, 5>(actw, wk + WOFF[3], acc5, biasl + 3 * 96, li, q);   // L3: K=96(86), DO=71
    epilogue<5>(acc5, actw, li, q);
    // after L3: cols 80..95 hold stale L2 outputs — harmless: W4^T cols d>=71 are zero.

    // L4 + fused head: e 0..63 (4 m-tiles), fp32 gelu dot hw, butterfly over q
    f32x4 acc4[4];
    layer_mm<3, 4>(actw, wk + WOFF[4], acc4, biasl + 4 * 96, li, q);
    float sum = 0.f;
#pragma unroll
    for (int mt = 0; mt < 4; mt++) {
        const int eb = mt * 16 + q * 4;
        f32x4 hh = *(const f32x4*)(headl + eb);
#pragma unroll
        for (int r = 0; r < 4; r++)
            sum += gelu_f(acc4[mt][r]) * hh[r];
    }
    sum += __shfl_xor(sum, 16);
    sum += __shfl_xor(sum, 32);
    sum += hb0;
    if (lane < 16) {
        int p = base + wv * 16 + lane;
        if (p < NPOS) {
            int b = p / NOUT, pos = p - b * NOUT;
            out[((size_t)(b * K_ + k)) * NOUT + pos] = sum;
        }
    }
}

extern "C" void kernel_launch(void* const* d_in, const int* in_sizes, int n_in,
                              void* d_out, int out_size, void* d_ws, size_t ws_size,
                              hipStream_t stream) {
    const float* x  = (const float*)d_in[0];
    const float* w0 = (const float*)d_in[1];  const float* b0 = (const float*)d_in[2];
    const float* w1 = (const float*)d_in[3];  const float* b1 = (const float*)d_in[4];
    const float* w2 = (const float*)d_in[5];  const float* b2 = (const float*)d_in[6];
    const float* w3 = (const float*)d_in[7];  const float* b3 = (const float*)d_in[8];
    const float* w4 = (const float*)d_in[9];  const float* b4 = (const float*)d_in[10];
    const float* hw = (const float*)d_in[11]; const float* hb = (const float*)d_in[12];
    float* out = (float*)d_out;
    f16* ws = (f16*)d_ws;

    const bool pre = (ws_size >= WS_NEED);     // 9.68 MB: weights 6.39 + act tiles 3.29

    if (pre) {
        (void)hipFuncSetAttribute((const void*)mlp_main<true>,
                                  hipFuncAttributeMaxDynamicSharedMemorySize, (int)SMEM_BYTES);
        prep_all<<<dim3(WUNITS + AUNITS), 256, 0, stream>>>(w0, w1, w2, w3, w4, x, ws);
        // grid x=k: linear id = k + 64*m -> XCD = k%8: all m-blocks of a k share one XCD's L2,
        // and all k-blocks of one m dispatch together (act tile stays L2-hot). This dispatch-
        // order locality is load-bearing (R15 lesson).
        mlp_main<true><<<dim3(K_, NBLK), TPB, SMEM_BYTES, stream>>>(
            x, b0, b1, b2, b3, b4, hw, hb, ws, out);
    } else {
        (void)hipFuncSetAttribute((const void*)mlp_main<false>,
                                  hipFuncAttributeMaxDynamicSharedMemorySize, (int)SMEM_BYTES);
        prep_all<<<dim3(WUNITS), 256, 0, stream>>>(w0, w1, w2, w3, w4, x, ws);
        mlp_main<false><<<dim3(K_, NBLK), TPB, SMEM_BYTES, stream>>>(
            x, b0, b1, b2, b3, b4, hw, hb, ws, out);
    }
}

// Round 7
// 248.790 us; speedup vs baseline: 1.4394x; 1.4394x over previous
//
#include <hip/hip_runtime.h>

typedef _Float16 f16;
typedef __attribute__((ext_vector_type(8))) _Float16 f16x8;
typedef __attribute__((ext_vector_type(2))) __fp16 hf16x2;   // native type of cvt_pkrtz
typedef __attribute__((ext_vector_type(4))) float f32x4;

constexpr int C_ = 4, L_ = 1000, K_ = 64, NOUT = 986, NPOS = 16 * 986; // 15776
constexpr int TPB  = 256;                       // 4 waves
constexpr int MTB  = 128;                       // positions per block (32/wave) — R16 geometry
constexpr int NBLK = (NPOS + MTB - 1) / MTB;    // 124
constexpr int AST  = 104;                       // row stride (f16): 208 B, 16B-aligned
constexpr int ACT_EL  = MTB * AST;              // 13312 f16
constexpr int WPAN_EL = 20 * 512;               // 10240 f16 LDS panel buf (20 x 1KB chunks)
// LDS: act 26624 + panel 20480 + bias(fp32) 1920 + head(fp32) 256 = 49280 B; 3 blocks/CU.
constexpr size_t SMEM_BYTES = (size_t)ACT_EL * 2 + (size_t)WPAN_EL * 2 + 480 * 4 + 64 * 4;

// ws: per layer l, per k: 96-row stride x AST cols fp16 W^T (row=out e, col=in d), zero-padded.
constexpr size_t WOFF[5]  = {0, 638976, 1277952, 1916928, 2555904};
constexpr int    WROWS[5] = {80, 96, 96, 80, 64};   // ceil16(DO)
constexpr int    DIv[5]   = {60, 72, 86, 86, 71};
constexpr int    DOv[5]   = {72, 86, 86, 71, 59};
// 1KB staging chunks per layer panel: ceil(WROWS*208/1024); partial chunks over-read into
// the (valid) 96-row slot and land inside the 20-chunk LDS buffer.
constexpr int    NCH[5]   = {17, 20, 20, 17, 13};
// Precomputed L0 activation tiles appended after the weights (x-gather is 64x redundant
// across k). Stored in EXACT LDS layout so the main loop copies them with global_load_lds.
constexpr size_t WTOT    = WOFF[4] + (size_t)K_ * 96 * AST;        // 3194880 f16
constexpr size_t ACT_WS  = WTOT;                                    // f16 index of tile region
constexpr size_t WS_NEED = (WTOT + (size_t)NBLK * ACT_EL) * 2;      // 9.69 MB

// prep decomposition (R16 structure): weight halves for 2x parallelism + act tile halves.
constexpr int WUNITS = 5 * K_ * 2;   // 640
constexpr int AUNITS = NBLK * 2;     // 248

__device__ __forceinline__ float gelu_f(float x) {
    // tanh-form gelu as x*sigmoid(2z); validated R4/R9/R10 (absmax 3.9e-3).
    // R12: -2*log2(e) folded into the polynomial constants -> direct v_exp_f32.
    float x2 = x * x;
    float ei = x * __builtin_fmaf(-0.1029433270f, x2, -2.3022082020f);
    float e  = __builtin_amdgcn_exp2f(ei);       // = exp(-2z)
    return x * __builtin_amdgcn_rcpf(e + 1.0f);
}

// R18: stage one layer's W^T panel global->LDS (1KB chunks split across the 4 waves).
// All 4 waves previously loaded IDENTICAL A addresses from global -> 4x redundant L2
// traffic, which R17 proved is the binding resource. Staged once per block instead.
__device__ __forceinline__ void stage_panel(const f16* __restrict__ src, f16* wpan,
                                            int nch, int wv, int lane) {
    for (int c = wv; c < nch; c += 4) {
        __builtin_amdgcn_global_load_lds(
            (const __attribute__((address_space(1))) void*)(src + c * 512 + lane * 8),
            (__attribute__((address_space(3))) void*)(wpan + c * 512), 16, 0, 0);
    }
}

// A = W^T fragments from the LDS panel (ds_read_b128, ~2-way bank aliasing = free).
// B = act rows from wave-private LDS. acc initialized with bias (e is lane-fixed in C).
template<int KSTEPS, int MT>
__device__ __forceinline__ void layer_mm_l(const f16* __restrict__ actw,
                                           const f16* __restrict__ wpan,
                                           f32x4 (&acc)[MT][2],
                                           const float* __restrict__ bl, int li, int q) {
#pragma unroll
    for (int mt = 0; mt < MT; mt++) {
        f32x4 bb = *(const f32x4*)(bl + mt * 16 + q * 4);   // broadcast across li
#pragma unroll
        for (int nt = 0; nt < 2; nt++) acc[mt][nt] = bb;
    }
#pragma unroll
    for (int ks = 0; ks < KSTEPS; ks++) {
        const int koff = ks * 32 + q * 8;
        f16x8 a[MT], b[2];
#pragma unroll
        for (int mt = 0; mt < MT; mt++)
            a[mt] = *(const f16x8*)(wpan + (mt * 16 + li) * AST + koff);   // ds_read_b128
#pragma unroll
        for (int nt = 0; nt < 2; nt++)
            b[nt] = *(const f16x8*)(actw + (nt * 16 + li) * AST + koff);   // ds_read_b128
#pragma unroll
        for (int mt = 0; mt < MT; mt++)
#pragma unroll
            for (int nt = 0; nt < 2; nt++)
                acc[mt][nt] = __builtin_amdgcn_mfma_f32_16x16x32_f16(a[mt], b[nt], acc[mt][nt], 0, 0, 0);
    }
}

// C/D: col(n=pos)=lane&15, row(m=e)=(lane>>4)*4+r -> lane owns 4 consecutive features of one
// position: gelu (bias already in acc) + pkrtz + one ds_write_b64. Rows are wave-private.
template<int MT>
__device__ __forceinline__ void epilogue(f32x4 (&acc)[MT][2], f16* __restrict__ actw,
                                         int li, int q) {
#pragma unroll
    for (int mt = 0; mt < MT; mt++) {
        const int eb = mt * 16 + q * 4;
#pragma unroll
        for (int nt = 0; nt < 2; nt++) {
            union { hf16x2 h[2]; unsigned long long u; } pk;
            pk.h[0] = __builtin_amdgcn_cvt_pkrtz(gelu_f(acc[mt][nt][0]),
                                                 gelu_f(acc[mt][nt][1]));
            pk.h[1] = __builtin_amdgcn_cvt_pkrtz(gelu_f(acc[mt][nt][2]),
                                                 gelu_f(acc[mt][nt][3]));
            f16* dst = actw + (nt * 16 + li) * AST + eb;   // 8B aligned
            *(unsigned long long*)dst = pk.u;
        }
    }
}

// R13 weight prep: coalesced load -> padded LDS transpose -> vector store; e-half split (R16).
template<int L>
__device__ __forceinline__ void prep_one_half(const float* __restrict__ wsrc0,
                                              f16* __restrict__ ws, f16* __restrict__ wl,
                                              int k, int h, int tid) {
    constexpr int DI = DIv[L], DO = DOv[L], RW = WROWS[L];
    const float* wsrc = wsrc0 + (size_t)k * DI * DO;
    constexpr int TOT = DI * DO;
    constexpr int NIT = (TOT + 255) / 256;
    float v[NIT];
#pragma unroll
    for (int it = 0; it < NIT; it++) {
        int i = tid + it * 256;
        v[it] = (i < TOT) ? wsrc[i] : 0.f;
    }
#pragma unroll
    for (int it = 0; it < NIT; it++) {
        int i = tid + it * 256;
        if (i < TOT) {
            int d = i / DO, e = i - d * DO;
            wl[d * 87 + e] = (f16)v[it];
        }
    }
    __syncthreads();
    f16* dst = ws + WOFF[L] + (size_t)k * 96 * AST;
    constexpr int HCH = (RW / 2) * 13;           // 16B chunks in this half
    constexpr int NIT2 = (HCH + 255) / 256;
#pragma unroll
    for (int it = 0; it < NIT2; it++) {
        int c0 = tid + it * 256;
        if (c0 < HCH) {
            int c = h * HCH + c0;
            int e = c / 13, db = (c - e * 13) * 8;
            f16x8 vv;
#pragma unroll
            for (int j = 0; j < 8; j++) {
                int d = db + j;
                vv[j] = (e < DO && d < DI) ? wl[d * 87 + e] : (f16)0.f;
            }
            *(f16x8*)(dst + (size_t)c * 8) = vv;
        }
    }
}

// Half of one mblk's L0 tile (chunked per 16B output). Cols 0..59 = x-window, 60..103 = zero
// (covers the K=64 pad AND cols 80..95 that K=96 loops read but MT=5 epilogues never write).
__device__ __forceinline__ void prep_act_half(const float* __restrict__ x,
                                              f16* __restrict__ dst0, int m, int h, int tid) {
    if (m >= NBLK) return;
    f16* dst = dst0 + (size_t)m * ACT_EL;
    const int base = m * MTB;
    constexpr int HCHK = MTB * 13 / 2;           // 832 chunks per half
    for (int i0 = tid; i0 < HCHK; i0 += 256) {
        int i = h * HCHK + i0;
        int r = i / 13, cc = (i - r * 13) * 8;
        int p = base + r; if (p > NPOS - 1) p = NPOS - 1;   // tail: duplicate last pos
        int b = p / NOUT, pos = p - b * NOUT;
        f16x8 vv;
#pragma unroll
        for (int j = 0; j < 8; j++) {
            int c = cc + j;
            float v = 0.f;
            if (c < 60) { int ch = c / 15, jj = c - ch * 15; v = x[(size_t)(b * C_ + ch) * L_ + pos + jj]; }
            vv[j] = (f16)v;
        }
        *(f16x8*)(dst + (size_t)r * AST + cc) = vv;
    }
}

// Flat prep grid: u < WUNITS -> weight half-panels; else act tile halves.
__global__ __launch_bounds__(256) void prep_all(
    const float* __restrict__ w0, const float* __restrict__ w1, const float* __restrict__ w2,
    const float* __restrict__ w3, const float* __restrict__ w4,
    const float* __restrict__ x, f16* __restrict__ ws) {
    __shared__ f16 wl[86 * 87];
    const int tid = threadIdx.x, u = blockIdx.x;
    if (u < WUNITS) {
        const int k = (u >> 1) & 63, h = u & 1;
        switch (u >> 7) {
            case 0: prep_one_half<0>(w0, ws, wl, k, h, tid); break;
            case 1: prep_one_half<1>(w1, ws, wl, k, h, tid); break;
            case 2: prep_one_half<2>(w2, ws, wl, k, h, tid); break;
            case 3: prep_one_half<3>(w3, ws, wl, k, h, tid); break;
            default: prep_one_half<4>(w4, ws, wl, k, h, tid); break;
        }
    } else {
        const int v = u - WUNITS;
        prep_act_half(x, ws + ACT_WS, v >> 1, v & 1, tid);
    }
}

// R18: __launch_bounds__(TPB,3) — 3 blocks/CU (LDS 49280/block). A comes from the staged
// LDS panel; staging of layer l+1 is issued right after the post-mm barrier and its latency
// hides under the epilogue's gelu VALU. 2 barriers per layer.
template<bool PRE>
__global__ __launch_bounds__(TPB, 3) void mlp_main(
    const float* __restrict__ x,
    const float* __restrict__ b0, const float* __restrict__ b1, const float* __restrict__ b2,
    const float* __restrict__ b3, const float* __restrict__ b4,
    const float* __restrict__ hw, const float* __restrict__ hb,
    const f16* __restrict__ ws, float* __restrict__ out) {
    extern __shared__ char smemraw[];
    f16*   act   = (f16*)smemraw;                 // [128 pos][AST]
    f16*   wpan  = act + ACT_EL;                  // staged layer panel (20 x 1KB)
    float* biasl = (float*)(wpan + WPAN_EL);      // 5 layers x 96 padded biases, fp32
    float* headl = biasl + 480;                   // 64 padded head weights, fp32

    const int tid = threadIdx.x, k = blockIdx.x, mblk = blockIdx.y;
    const int wv = tid >> 6, lane = tid & 63, li = lane & 15, q = lane >> 4;
    const int base = mblk * MTB;
    f16* actw = act + (wv * 32) * AST;            // this wave's 32 position rows
    const f16* wk = ws + (size_t)k * 96 * AST;    // k's weight panel base (per-layer via WOFF)

    stage_panel(wk + WOFF[0], wpan, NCH[0], wv, lane);   // L0 panel under act/bias staging

    // biases (padded to 96, fp32) + head weights into LDS
    for (int i = tid; i < 480; i += TPB) {
        int l = i / 96, e = i - l * 96;
        const float* bg = (l == 0) ? b0 : (l == 1) ? b1 : (l == 2) ? b2 : (l == 3) ? b3 : b4;
        int DO = (l == 0) ? 72 : (l == 1) ? 86 : (l == 2) ? 86 : (l == 3) ? 71 : 59;
        biasl[i] = (e < DO) ? bg[k * DO + e] : 0.f;
    }
    if (tid < 64) headl[tid] = (tid < 59) ? hw[tid] : 0.f;

    if constexpr (PRE) {
        // direct global->LDS copy of the precomputed tile: 26624 B = 26 x (64 lanes x 16 B).
        const f16* src = ws + ACT_WS + (size_t)mblk * ACT_EL;
        for (int c = wv; c < 26; c += 4) {
            __builtin_amdgcn_global_load_lds(
                (const __attribute__((address_space(1))) void*)(src + c * 512 + lane * 8),
                (__attribute__((address_space(3))) void*)(act + c * 512), 16, 0, 0);
        }
    } else {
        // fallback (ws too small): in-kernel gather.
        const int b0i = base / NOUT;
        const int thr = (b0i + 1) * NOUT;
        for (int i = tid; i < 64 * MTB; i += TPB) {
            int d = i >> 7, r = i & (MTB - 1);
            int p = base + r; if (p > NPOS - 1) p = NPOS - 1;
            int b = (p >= thr) ? b0i + 1 : b0i;
            int pos = p - b * NOUT;
            float v = 0.f;
            if (d < 60) { int c = d / 15, j = d - c * 15; v = x[(size_t)(b * C_ + c) * L_ + pos + j]; }
            act[r * AST + d] = (f16)v;
        }
        for (int i = tid; i < MTB * 2; i += TPB) {
            int r = i >> 1, cc = (i & 1) << 3;
            *(f16x8*)(act + r * AST + 80 + cc) = f16x8{0,0,0,0,0,0,0,0};
        }
    }
    const float hb0 = hb[0];
    __syncthreads();     // drains vmcnt: act tile + L0 panel resident

    f32x4 acc[6][2];
    f32x4 (&acc5)[5][2] = reinterpret_cast<f32x4 (&)[5][2]>(acc);

    layer_mm_l<2, 5>(actw, wpan, acc5, biasl + 0 * 96, li, q);   // L0: K=64, DO=72
    __syncthreads();                                  // all waves done reading wpan(L0)
    stage_panel(wk + WOFF[1], wpan, NCH[1], wv, lane);
    epilogue<5>(acc5, actw, li, q);                   // gelu VALU hides staging latency
    __syncthreads();                                  // drains vmcnt: wpan = W1

    layer_mm_l<3, 6>(actw, wpan, acc, biasl + 1 * 96, li, q);    // L1: K=96(72), DO=86
    __syncthreads();
    stage_panel(wk + WOFF[2], wpan, NCH[2], wv, lane);
    epilogue<6>(acc, actw, li, q);
    __syncthreads();

    layer_mm_l<3, 6>(actw, wpan, acc, biasl + 2 * 96, li, q);    // L2: K=96(86), DO=86
    __syncthreads();
    stage_panel(wk + WOFF[3], wpan, NCH[3], wv, lane);
    epilogue<6>(acc, actw, li, q);
    __syncthreads();

    layer_mm_l<3, 5>(actw, wpan, acc5, biasl + 3 * 96, li, q);   // L3: K=96(86), DO=71
    __syncthreads();
    stage_panel(wk + WOFF[4], wpan, NCH[4], wv, lane);
    epilogue<5>(acc5, actw, li, q);
    __syncthreads();
    // after L3: act cols 80..95 hold stale L2 outputs — harmless: W4^T cols d>=71 are zero.

    // L4 + fused head: e 0..63 (4 m-tiles), fp32 gelu dot hw, butterfly over q
    f32x4 acc4[4][2];
    layer_mm_l<3, 4>(actw, wpan, acc4, biasl + 4 * 96, li, q);
    float sum[2] = {0.f, 0.f};
#pragma unroll
    for (int mt = 0; mt < 4; mt++) {
        const int eb = mt * 16 + q * 4;
        f32x4 hh = *(const f32x4*)(headl + eb);
#pragma unroll
        for (int nt = 0; nt < 2; nt++) {
#pragma unroll
            for (int r = 0; r < 4; r++)
                sum[nt] += gelu_f(acc4[mt][nt][r]) * hh[r];
        }
    }
#pragma unroll
    for (int nt = 0; nt < 2; nt++) {
        float s = sum[nt];
        s += __shfl_xor(s, 16);
        s += __shfl_xor(s, 32);
        s += hb0;
        if (lane < 16) {
            int p = base + wv * 32 + nt * 16 + lane;
            if (p < NPOS) {
                int b = p / NOUT, pos = p - b * NOUT;
                out[((size_t)(b * K_ + k)) * NOUT + pos] = s;
            }
        }
    }
}

extern "C" void kernel_launch(void* const* d_in, const int* in_sizes, int n_in,
                              void* d_out, int out_size, void* d_ws, size_t ws_size,
                              hipStream_t stream) {
    const float* x  = (const float*)d_in[0];
    const float* w0 = (const float*)d_in[1];  const float* b0 = (const float*)d_in[2];
    const float* w1 = (const float*)d_in[3];  const float* b1 = (const float*)d_in[4];
    const float* w2 = (const float*)d_in[5];  const float* b2 = (const float*)d_in[6];
    const float* w3 = (const float*)d_in[7];  const float* b3 = (const float*)d_in[8];
    const float* w4 = (const float*)d_in[9];  const float* b4 = (const float*)d_in[10];
    const float* hw = (const float*)d_in[11]; const float* hb = (const float*)d_in[12];
    float* out = (float*)d_out;
    f16* ws = (f16*)d_ws;

    const bool pre = (ws_size >= WS_NEED);     // 9.69 MB: weights 6.39 + act tiles 3.30

    if (pre) {
        (void)hipFuncSetAttribute((const void*)mlp_main<true>,
                                  hipFuncAttributeMaxDynamicSharedMemorySize, (int)SMEM_BYTES);
        prep_all<<<dim3(WUNITS + AUNITS), 256, 0, stream>>>(w0, w1, w2, w3, w4, x, ws);
        // grid x=k: linear id = k + 64*m -> XCD = k%8: all m-blocks of a k share one XCD's L2,
        // and all k-blocks of one m dispatch together (act tile stays L2-hot). This dispatch-
        // order locality is load-bearing (R15 lesson).
        mlp_main<true><<<dim3(K_, NBLK), TPB, SMEM_BYTES, stream>>>(
            x, b0, b1, b2, b3, b4, hw, hb, ws, out);
    } else {
        (void)hipFuncSetAttribute((const void*)mlp_main<false>,
                                  hipFuncAttributeMaxDynamicSharedMemorySize, (int)SMEM_BYTES);
        prep_all<<<dim3(WUNITS), 256, 0, stream>>>(w0, w1, w2, w3, w4, x, ws);
        mlp_main<false><<<dim3(K_, NBLK), TPB, SMEM_BYTES, stream>>>(
            x, b0, b1, b2, b3, b4, hw, hb, ws, out);
    }
}